// Round 9
// baseline (966.067 us; speedup 1.0000x reference)
//
#include <hip/hip_runtime.h>
#include <hip/hip_fp16.h>
#include <math.h>

// BatchSpectralLoss: out = lambda_max(A^T A), A = 8192x4096 fp32 (k==1).
// SINGLE fused kernel, fence-free barrier, register-resident A, CACHED reads.
// Ladder: R2 1366us (acquire-spin inv/poll) -> R5 1249 (bypass spin) ->
// R7 907 (no wbl2 release fences; write-through + bypass reads) ->
// R8 770 kernel (A in registers; FETCH 1.05GB->545MB).
// R8 post-mortem: VALU 5.6%, HBM 14%, yet 45us/step of wait. 909MB / 16B
// bypass requests / 770us ~= 31 req/cycle = TCC request-rate ceiling. The
// sc0sc1 bypass READS are request-rate-bound and defeat all L2 reuse (v read
// 64x per XCD). With A in registers, L2 holds NO precious state -> a bulk
// L2 inv per barrier is ~free (R2's cost was inv-per-POLL, 100x more).
// THIS round: reads of v/partials/slots/rc/rp = NORMAL CACHED loads; one
// fence(ACQUIRE,"agent") (bulk L1+L2 inv) at each barrier exit guarantees
// freshness (data was written through to IC; local copies dropped at the
// barrier between write and read; first barrier also kills cross-launch
// staleness). Writes stay write-through sc0sc1 (no dirty lines -> no wbl2).
// Spin stays bypass (cached spin would never observe remote stores).
//
// ws float layout: vb0/vb1/vb2 at 0/4096/8192, slots at 12288
//   (alpha[j]=slots[j], norm2[j]=slots[64+j]), barrier at 12416
//   (8 arrive counters 64B-spaced, release gen at uint +192, err at +200;
//   1024B memset each launch), partials at 262144 (512x4096, ends 9 MiB).

#define NROWS 8192
#define NCOLS 4096
#define T_STEPS 16
#define NBLK 512
#define RPB 16           // rows per block (8192 / 512)
#define SPIN_LIMIT 200000L

typedef float f32x4_t __attribute__((ext_vector_type(4)));

// ---- coherence-point (Infinity Cache) accessors for SYNC state only
__device__ __forceinline__ unsigned ic_ld_u32(const unsigned* p) {
    unsigned v;
    asm volatile("global_load_dword %0, %1, off sc0 sc1\n\ts_waitcnt vmcnt(0)"
                 : "=v"(v) : "v"(p) : "memory");
    return v;
}
__device__ __forceinline__ void ic_st_u32(unsigned* p, unsigned v) {
    asm volatile("global_store_dword %0, %1, off sc0 sc1"
                 :: "v"(p), "v"(v) : "memory");
}
__device__ __forceinline__ void ic_st_f32(float* p, float v) {
    asm volatile("global_store_dword %0, %1, off sc0 sc1"
                 :: "v"(p), "v"(v) : "memory");
}
__device__ __forceinline__ void ic_st4_f32(float* p, float4 v) {
    f32x4_t x; x.x = v.x; x.y = v.y; x.z = v.z; x.w = v.w;
    asm volatile("global_store_dwordx4 %0, %1, off sc0 sc1"
                 :: "v"(p), "v"(x) : "memory");
}
__device__ __forceinline__ unsigned ic_sum4_u32(const unsigned* p0, const unsigned* p1,
                                                const unsigned* p2, const unsigned* p3) {
    unsigned a, b, c, d;
    asm volatile(
        "global_load_dword %0, %4, off sc0 sc1\n\t"
        "global_load_dword %1, %5, off sc0 sc1\n\t"
        "global_load_dword %2, %6, off sc0 sc1\n\t"
        "global_load_dword %3, %7, off sc0 sc1\n\t"
        "s_waitcnt vmcnt(0)"
        : "=&v"(a), "=&v"(b), "=&v"(c), "=&v"(d)
        : "v"(p0), "v"(p1), "v"(p2), "v"(p3) : "memory");
    return a + b + c + d;
}

__device__ __forceinline__ void up8(const float4& p, float* f) {
    const __half2* h = (const __half2*)&p;
    float2 t0 = __half22float2(h[0]);
    float2 t1 = __half22float2(h[1]);
    float2 t2 = __half22float2(h[2]);
    float2 t3 = __half22float2(h[3]);
    f[0] = t0.x; f[1] = t0.y; f[2] = t1.x; f[3] = t1.y;
    f[4] = t2.x; f[5] = t2.y; f[6] = t3.x; f[7] = t3.y;
}
__device__ __forceinline__ float4 pack8(const float4& a, const float4& b) {
    union { float4 f4; __half2 h2[4]; } u;
    u.h2[0] = __halves2half2(__float2half_rn(a.x), __float2half_rn(a.y));
    u.h2[1] = __halves2half2(__float2half_rn(a.z), __float2half_rn(a.w));
    u.h2[2] = __halves2half2(__float2half_rn(b.x), __float2half_rn(b.y));
    u.h2[3] = __halves2half2(__float2half_rn(b.z), __float2half_rn(b.w));
    return u.f4;
}

// Grid barrier: fence-free arrive/spin (R7-proven) + ONE bulk L1/L2
// invalidate on exit so subsequent NORMAL cached loads observe everything
// written through to the IC before the barrier. With A register-resident,
// the inv evicts only single-use stream data -> ~free.
__device__ __forceinline__ void gbar(unsigned* arrive, unsigned* release,
                                     unsigned* errw, unsigned gen, int bid) {
    __syncthreads();   // each wave drains its own vmcnt before s_barrier
    if (threadIdx.x == 0) {
        asm volatile("s_waitcnt vmcnt(0)" ::: "memory");
        __hip_atomic_fetch_add(&arrive[(bid & 7) * 16], 1u,
                               __ATOMIC_RELAXED, __HIP_MEMORY_SCOPE_AGENT);
        if (ic_ld_u32(errw) == 0) {
            long iters = 0;
            if (bid == 0) {
                const unsigned target = gen * NBLK;
                for (;;) {
                    unsigned s = ic_sum4_u32(&arrive[0], &arrive[16], &arrive[32], &arrive[48])
                               + ic_sum4_u32(&arrive[64], &arrive[80], &arrive[96], &arrive[112]);
                    if (s >= target) break;
                    if (++iters > SPIN_LIMIT) { ic_st_u32(errw, gen); break; }
                    if ((iters & 255) == 0 && ic_ld_u32(errw)) break;
                    __builtin_amdgcn_s_sleep(2);
                }
                ic_st_u32(release, gen);
            } else {
                while (ic_ld_u32(release) < gen) {
                    if (++iters > SPIN_LIMIT) { ic_st_u32(errw, gen); break; }
                    if ((iters & 255) == 0 && ic_ld_u32(errw)) break;
                    __builtin_amdgcn_s_sleep(2);
                }
            }
        }
        __builtin_amdgcn_fence(__ATOMIC_ACQUIRE, "agent");   // bulk L1+L2 inv
    }
    __syncthreads();
}

__global__ __launch_bounds__(256, 2) void lanczos_fused(const float* __restrict__ A,
                                                        float* __restrict__ ws,
                                                        float* __restrict__ out) {
    __shared__ __align__(16) float smem[192];
    float* slots = ws + 12288;
    unsigned* arrive = (unsigned*)(ws + 12416);
    unsigned* release = (unsigned*)(ws + 12416) + 192;
    unsigned* errw = (unsigned*)(ws + 12416) + 200;
    float* partials = ws + 262144;
    const int tid = threadIdx.x;
    const int bid = blockIdx.x;
    const int gtid = bid * 256 + tid;
    const int cA = tid * 8, cB = 2048 + tid * 8;
    unsigned gen = 0;

    // --- Phase A: load this thread's A-slice into registers (fp32->fp16) ----
    // Thread owns rows [bid*16, bid*16+16) x cols [cA,cA+8) u [cB,cB+8).
    float4 arA[RPB], arB[RPB];
    {
        const float* base = A + (size_t)bid * RPB * NCOLS;
#pragma unroll
        for (int r = 0; r < RPB; ++r) {
            const float* rowp = base + (size_t)r * NCOLS;
            float4 a0 = *(const float4*)(rowp + cA);
            float4 a1 = *(const float4*)(rowp + cA + 4);
            float4 b0 = *(const float4*)(rowp + cB);
            float4 b1 = *(const float4*)(rowp + cB + 4);
            arA[r] = pack8(a0, a1);
            arB[r] = pack8(b0, b1);
        }
        if (gtid < NCOLS) {
            unsigned h = (unsigned)gtid * 2654435761u;
            h ^= h >> 16; h *= 2246822519u; h ^= h >> 13;
            ic_st_f32(ws + 4096 + gtid, (h & 1u) ? 0.015625f : -0.015625f); // vb[1]
            ic_st_f32(ws + gtid, 0.f);                                      // vb[0]
            if (gtid < 128)
                ic_st_f32(slots + gtid, (gtid == 64 || gtid == 65) ? 1.f : 0.f);
        }
    }
    gbar(arrive, release, errw, ++gen, bid);

    for (int j = 1; j <= T_STEPS; ++j) {
        const float* rc = ws + 4096 * (j % 3);
        const float* rp = ws + 4096 * ((j + 2) % 3);
        float* wt = ws + 4096 * ((j + 1) % 3);

        // ---------------- bmv phase: partials = per-block A^T(Av), alpha ----
        {
            int lane = tid & 63;
            float inv = rsqrtf(fmaxf(slots[64 + j], 1e-30f));   // cached, fresh
            float vA[8], vB[8];
            {
                float4 x = *(const float4*)(rc + cA);           // cached, fresh
                float4 y = *(const float4*)(rc + cA + 4);
                float4 z = *(const float4*)(rc + cB);
                float4 w4 = *(const float4*)(rc + cB + 4);
                vA[0] = x.x * inv; vA[1] = x.y * inv; vA[2] = x.z * inv; vA[3] = x.w * inv;
                vA[4] = y.x * inv; vA[5] = y.y * inv; vA[6] = y.z * inv; vA[7] = y.w * inv;
                vB[0] = z.x * inv; vB[1] = z.y * inv; vB[2] = z.z * inv; vB[3] = z.w * inv;
                vB[4] = w4.x * inv; vB[5] = w4.y * inv; vB[6] = w4.z * inv; vB[7] = w4.w * inv;
            }
            __syncthreads();                  // prior phase's smem readers done
            if (tid < RPB) smem[tid] = 0.f;
            __syncthreads();
#pragma unroll
            for (int r = 0; r < RPB; ++r) {   // row dots (A from registers)
                float f[8];
                up8(arA[r], f);
                float sp = f[0] * vA[0] + f[1] * vA[1] + f[2] * vA[2] + f[3] * vA[3]
                         + f[4] * vA[4] + f[5] * vA[5] + f[6] * vA[6] + f[7] * vA[7];
                up8(arB[r], f);
                sp += f[0] * vB[0] + f[1] * vB[1] + f[2] * vB[2] + f[3] * vB[3]
                    + f[4] * vB[4] + f[5] * vB[5] + f[6] * vB[6] + f[7] * vB[7];
#pragma unroll
                for (int off = 32; off > 0; off >>= 1) sp += __shfl_xor(sp, off);
                if (lane == 0) atomicAdd(&smem[r], sp);
            }
            __syncthreads();
            if (tid == 0) {                   // alpha += sum_r s_r^2 (1 atomic)
                float aa = 0.f;
#pragma unroll
                for (int r = 0; r < RPB; ++r) aa += smem[r] * smem[r];
                atomicAdd(&slots[j], aa);
            }
            float wacc[16];
#pragma unroll
            for (int i = 0; i < 16; ++i) wacc[i] = 0.f;
#pragma unroll
            for (int r = 0; r < RPB; ++r) {   // w += s_r * A_r (per-thread)
                float s = smem[r];
                float f[8];
                up8(arA[r], f);
                wacc[0] += s * f[0]; wacc[1] += s * f[1]; wacc[2] += s * f[2]; wacc[3] += s * f[3];
                wacc[4] += s * f[4]; wacc[5] += s * f[5]; wacc[6] += s * f[6]; wacc[7] += s * f[7];
                up8(arB[r], f);
                wacc[8] += s * f[0]; wacc[9] += s * f[1]; wacc[10] += s * f[2]; wacc[11] += s * f[3];
                wacc[12] += s * f[4]; wacc[13] += s * f[5]; wacc[14] += s * f[6]; wacc[15] += s * f[7];
            }
            float* pb = partials + (size_t)bid * NCOLS;        // write-through
            ic_st4_f32(pb + cA,     make_float4(wacc[0], wacc[1], wacc[2], wacc[3]));
            ic_st4_f32(pb + cA + 4, make_float4(wacc[4], wacc[5], wacc[6], wacc[7]));
            ic_st4_f32(pb + cB,     make_float4(wacc[8], wacc[9], wacc[10], wacc[11]));
            ic_st4_f32(pb + cB + 4, make_float4(wacc[12], wacc[13], wacc[14], wacc[15]));
        }
        gbar(arrive, release, errw, ++gen, bid);

        if (j < T_STEPS) {
            // ------------- fused reduce: 512 partials -> w, recurrence, beta --
            // Block b owns cols [8b, 8b+8). Thread: q=tid&1 (col-quad),
            // p0=tid>>1; sums partial rows {p0, p0+128, p0+256, p0+384}.
            {
                int q = tid & 1, p0 = tid >> 1;
                const float* pb0 = partials + (size_t)p0 * NCOLS + bid * 8 + q * 4;
                float4 v0 = *(const float4*)(pb0);              // cached, fresh
                float4 v1 = *(const float4*)(pb0 + (size_t)128 * NCOLS);
                float4 v2 = *(const float4*)(pb0 + (size_t)256 * NCOLS);
                float4 v3 = *(const float4*)(pb0 + (size_t)384 * NCOLS);
                float4 s;
                s.x = v0.x + v1.x + v2.x + v3.x;
                s.y = v0.y + v1.y + v2.y + v3.y;
                s.z = v0.z + v1.z + v2.z + v3.z;
                s.w = v0.w + v1.w + v2.w + v3.w;
#pragma unroll
                for (int off = 2; off <= 32; off <<= 1) {
                    s.x += __shfl_xor(s.x, off);
                    s.y += __shfl_xor(s.y, off);
                    s.z += __shfl_xor(s.z, off);
                    s.w += __shfl_xor(s.w, off);
                }
                int lane = tid & 63, wv = tid >> 6;
                __syncthreads();              // bmv smem readers done
                if (lane < 2) *(float4*)&smem[32 + wv * 8 + lane * 4] = s;
                __syncthreads();
                if (tid < 8) {
                    int col = bid * 8 + tid;
                    float wsum = smem[32 + tid] + smem[40 + tid] + smem[48 + tid] + smem[56 + tid];
                    float a = slots[j];                          // cached, fresh
                    float n2j = fmaxf(slots[64 + j], 1e-30f);
                    float n2m = fmaxf(slots[64 + j - 1], 1e-30f);
                    float invj = rsqrtf(n2j);
                    float cb = sqrtf(n2j / n2m);                 // beta ratio
                    float rn = wsum - a * invj * rc[col] - cb * rp[col];
                    ic_st_f32(&wt[col], rn);                     // write-through
                    float p = rn * rn;
                    p += __shfl_xor(p, 1);
                    p += __shfl_xor(p, 2);
                    p += __shfl_xor(p, 4);
                    if (tid == 0) atomicAdd(&slots[64 + j + 1], p);
                }
            }
            gbar(arrive, release, errw, ++gen, bid);
        }
    }

    // ---------------- solve: largest eig of tridiag via Sturm (block 0) -------
    if (bid == 0) {
        const int t = T_STEPS;
        float* d_s = smem;
        float* e2_s = smem + 64;
        if (tid < 64) {
            d_s[tid] = (tid < t) ? slots[1 + tid] : 0.f;         // cached, fresh
            e2_s[tid] = (tid < t - 1) ? slots[64 + tid + 2] : 0.f;
        }
        __syncthreads();
        if (tid < 64) {
            int lane = tid;
            float e_here = sqrtf(e2_s[lane]);
            float e_prev = (lane > 0) ? sqrtf(e2_s[lane - 1]) : 0.f;
            float d = d_s[lane];
            float gersh = (lane < t) ? d + e_here + e_prev : 0.f;
            float dmax = (lane < t) ? d : 0.f;
#pragma unroll
            for (int off = 32; off > 0; off >>= 1) {
                gersh = fmaxf(gersh, __shfl_xor(gersh, off));
                dmax = fmaxf(dmax, __shfl_xor(dmax, off));
            }
            float lo = dmax, hi = gersh + 1e-3f;
            for (int round = 0; round < 3; ++round) {
                float stepw = (hi - lo) * (1.f / 64.f);
                float x = lo + stepw * (lane + 1);
                double qv = 1.0;
                int cnt = 0;
                for (int i = 0; i < t; ++i) {
                    double qi = (double)d_s[i] - (double)x - ((i > 0) ? (double)e2_s[i - 1] / qv : 0.0);
                    if (fabs(qi) < 1e-300) qi = -1e-300;
                    cnt += (qi < 0.0);
                    qv = qi;
                }
                unsigned long long m = __ballot(cnt < t);
                if (m) {
                    int h = 63 - __clzll(m);
                    lo = lo + stepw * (h + 1);
                    hi = lo + stepw;
                } else {
                    hi = lo + stepw;
                }
            }
            if (tid == 0) {
                unsigned e = ic_ld_u32(errw);
                out[0] = e ? (-1.0e7f - (float)e) : 0.5f * (lo + hi);
            }
        }
    }
}

extern "C" void kernel_launch(void* const* d_in, const int* in_sizes, int n_in,
                              void* d_out, int out_size, void* d_ws, size_t ws_size,
                              hipStream_t stream) {
    const float* A = (const float*)d_in[0];
    float* out = (float*)d_out;
    float* ws = (float*)d_ws;

    // Zero barrier state: arrive counters + release gen + err (1024 B).
    hipMemsetAsync((char*)d_ws + (size_t)12416 * 4, 0, 1024, stream);

    lanczos_fused<<<NBLK, 256, 0, stream>>>(A, ws, out);
}

// Round 10
// 945.810 us; speedup vs baseline: 1.0214x; 1.0214x over previous
//
#include <hip/hip_runtime.h>
#include <hip/hip_fp16.h>
#include <math.h>

// BatchSpectralLoss: out = lambda_max(A^T A), A = 8192x4096 fp32 (k==1).
// SINGLE fused kernel, fence-free barrier, register-resident A, DISTRIBUTED
// barrier state.
// Ladder: R2 1366 (acquire-spin inv/poll) -> R5 1249 (bypass spin) -> R7 907
// (no wbl2 release fences) -> R8 770 kernel (A in registers, all-bypass) ->
// R9 840 REGRESSION (cached reads + per-block acquire fence: staggered
// per-block buffer_inv destroyed the very reuse it enabled; FETCH unmoved).
// R9 lesson: NO per-block cache ops, ever. R8 data path restored.
// R8 residual (~20us/barrier idle): 511 spinners poll ONE release line with
// bypass loads every ~0.4us => ~1300 same-line uncached req/us saturate one
// TCC slice; arrivals queue behind the flood. THIS round distributes it:
// 64 arrive counters (8 RMWs each), block0 polls all 64 with one WAVE
// (lane l loads line l, shfl-sum), release fanned out to 64 lines by
// block0's wave, spinner b polls line b&63 (8 blocks/line) with s_sleep(16).
// Bounded spin + sticky err sentinel kept (failure => out=-1e7-gen).
//
// ws float layout: vb0/vb1/vb2 at 0/4096/8192, slots at 12288
//   (alpha[j]=slots[j], norm2[j]=slots[64+j]), barrier at 12416:
//   arrive = 64 lines x 16 uints, release = 64 lines x 16 uints at +1024,
//   err at +2048 (12 KiB memset each launch), partials at 262144 (512x4096).

#define NROWS 8192
#define NCOLS 4096
#define T_STEPS 16
#define NBLK 512
#define RPB 16           // rows per block (8192 / 512)
#define SPIN_LIMIT 200000L

typedef float f32x4_t __attribute__((ext_vector_type(4)));

// ---- coherence-point (Infinity Cache) accessors: bypass L1+L2, no cache ops
__device__ __forceinline__ unsigned ic_ld_u32(const unsigned* p) {
    unsigned v;
    asm volatile("global_load_dword %0, %1, off sc0 sc1\n\ts_waitcnt vmcnt(0)"
                 : "=v"(v) : "v"(p) : "memory");
    return v;
}
__device__ __forceinline__ float ic_ld_f32(const float* p) {
    float v;
    asm volatile("global_load_dword %0, %1, off sc0 sc1\n\ts_waitcnt vmcnt(0)"
                 : "=v"(v) : "v"(p) : "memory");
    return v;
}
__device__ __forceinline__ void ic_st_u32(unsigned* p, unsigned v) {
    asm volatile("global_store_dword %0, %1, off sc0 sc1"
                 :: "v"(p), "v"(v) : "memory");
}
__device__ __forceinline__ void ic_st_f32(float* p, float v) {
    asm volatile("global_store_dword %0, %1, off sc0 sc1"
                 :: "v"(p), "v"(v) : "memory");
}
__device__ __forceinline__ void ic_st4_f32(float* p, float4 v) {
    f32x4_t x; x.x = v.x; x.y = v.y; x.z = v.z; x.w = v.w;
    asm volatile("global_store_dwordx4 %0, %1, off sc0 sc1"
                 :: "v"(p), "v"(x) : "memory");
}
__device__ __forceinline__ void ic_ld4_f32x4(const float* p0, const float* p1,
                                             const float* p2, const float* p3,
                                             float4& ao, float4& bo, float4& co, float4& do_) {
    f32x4_t a, b, c, d;
    asm volatile(
        "global_load_dwordx4 %0, %4, off sc0 sc1\n\t"
        "global_load_dwordx4 %1, %5, off sc0 sc1\n\t"
        "global_load_dwordx4 %2, %6, off sc0 sc1\n\t"
        "global_load_dwordx4 %3, %7, off sc0 sc1\n\t"
        "s_waitcnt vmcnt(0)"
        : "=&v"(a), "=&v"(b), "=&v"(c), "=&v"(d)
        : "v"(p0), "v"(p1), "v"(p2), "v"(p3) : "memory");
    ao = make_float4(a.x, a.y, a.z, a.w);
    bo = make_float4(b.x, b.y, b.z, b.w);
    co = make_float4(c.x, c.y, c.z, c.w);
    do_ = make_float4(d.x, d.y, d.z, d.w);
}

__device__ __forceinline__ void up8(const float4& p, float* f) {
    const __half2* h = (const __half2*)&p;
    float2 t0 = __half22float2(h[0]);
    float2 t1 = __half22float2(h[1]);
    float2 t2 = __half22float2(h[2]);
    float2 t3 = __half22float2(h[3]);
    f[0] = t0.x; f[1] = t0.y; f[2] = t1.x; f[3] = t1.y;
    f[4] = t2.x; f[5] = t2.y; f[6] = t3.x; f[7] = t3.y;
}
__device__ __forceinline__ float4 pack8(const float4& a, const float4& b) {
    union { float4 f4; __half2 h2[4]; } u;
    u.h2[0] = __halves2half2(__float2half_rn(a.x), __float2half_rn(a.y));
    u.h2[1] = __halves2half2(__float2half_rn(a.z), __float2half_rn(a.w));
    u.h2[2] = __halves2half2(__float2half_rn(b.x), __float2half_rn(b.y));
    u.h2[3] = __halves2half2(__float2half_rn(b.z), __float2half_rn(b.w));
    return u.f4;
}

// Distributed fence-free grid barrier. arrive: 64 lines (8 RMWs each).
// block0 polls with a full wave (lane l -> line l, shfl-sum). release:
// fanned out to 64 lines; spinner b polls line b&63 with long sleeps.
__device__ __forceinline__ void gbar(unsigned* arrive, unsigned* release,
                                     unsigned* errw, unsigned gen, int bid) {
    const int tid = threadIdx.x;
    __syncthreads();
    if (tid < 64) {
        if (tid == 0) {
            asm volatile("s_waitcnt vmcnt(0)" ::: "memory");  // write-throughs at IC
            __hip_atomic_fetch_add(&arrive[(bid & 63) * 16], 1u,
                                   __ATOMIC_RELAXED, __HIP_MEMORY_SCOPE_AGENT);
        }
        if (bid == 0) {
            const unsigned target = gen * NBLK;
            long iters = 0;
            for (;;) {
                unsigned v = ic_ld_u32(&arrive[tid * 16]);
#pragma unroll
                for (int off = 32; off > 0; off >>= 1)
                    v += (unsigned)__shfl_xor((int)v, off);
                if (v >= target) break;                       // uniform across wave
                int bail = 0;
                if (tid == 0) {
                    if (++iters > SPIN_LIMIT) { ic_st_u32(errw, gen); bail = 1; }
                    else if ((iters & 255) == 0 && ic_ld_u32(errw)) bail = 1;
                }
                if (__shfl(bail, 0)) break;
                __builtin_amdgcn_s_sleep(1);
            }
            ic_st_u32(&release[tid * 16], gen);               // 64-line fan-out
        } else if (tid == 0) {
            long iters = 0;
            while (ic_ld_u32(&release[(bid & 63) * 16]) < gen) {
                if (++iters > SPIN_LIMIT) { ic_st_u32(errw, gen); break; }
                if ((iters & 63) == 0 && ic_ld_u32(errw)) break;
                __builtin_amdgcn_s_sleep(16);
            }
        }
    }
    __syncthreads();
}

__global__ __launch_bounds__(256, 2) void lanczos_fused(const float* __restrict__ A,
                                                        float* __restrict__ ws,
                                                        float* __restrict__ out) {
    __shared__ __align__(16) float smem[192];
    float* slots = ws + 12288;
    unsigned* arrive = (unsigned*)(ws + 12416);          // 64 lines
    unsigned* release = (unsigned*)(ws + 12416) + 1024;  // 64 lines
    unsigned* errw = (unsigned*)(ws + 12416) + 2048;
    float* partials = ws + 262144;
    const int tid = threadIdx.x;
    const int bid = blockIdx.x;
    const int gtid = bid * 256 + tid;
    const int cA = tid * 8, cB = 2048 + tid * 8;
    unsigned gen = 0;

    // --- Phase A: load this thread's A-slice into registers (fp32->fp16) ----
    // Thread owns rows [bid*16, bid*16+16) x cols [cA,cA+8) u [cB,cB+8).
    float4 arA[RPB], arB[RPB];
    {
        const float* base = A + (size_t)bid * RPB * NCOLS;
#pragma unroll
        for (int r = 0; r < RPB; ++r) {
            const float* rowp = base + (size_t)r * NCOLS;
            float4 a0 = *(const float4*)(rowp + cA);
            float4 a1 = *(const float4*)(rowp + cA + 4);
            float4 b0 = *(const float4*)(rowp + cB);
            float4 b1 = *(const float4*)(rowp + cB + 4);
            arA[r] = pack8(a0, a1);
            arB[r] = pack8(b0, b1);
        }
        if (gtid < NCOLS) {
            unsigned h = (unsigned)gtid * 2654435761u;
            h ^= h >> 16; h *= 2246822519u; h ^= h >> 13;
            ic_st_f32(ws + 4096 + gtid, (h & 1u) ? 0.015625f : -0.015625f); // vb[1]
            ic_st_f32(ws + gtid, 0.f);                                      // vb[0]
            if (gtid < 128)
                ic_st_f32(slots + gtid, (gtid == 64 || gtid == 65) ? 1.f : 0.f);
        }
    }
    gbar(arrive, release, errw, ++gen, bid);

    for (int j = 1; j <= T_STEPS; ++j) {
        const float* rc = ws + 4096 * (j % 3);
        const float* rp = ws + 4096 * ((j + 2) % 3);
        float* wt = ws + 4096 * ((j + 1) % 3);

        // ---------------- bmv phase: partials = per-block A^T(Av), alpha ----
        {
            int lane = tid & 63;
            float inv = rsqrtf(fmaxf(ic_ld_f32(&slots[64 + j]), 1e-30f));
            float vA[8], vB[8];
            {
                float4 x, y, z, w4;
                ic_ld4_f32x4(rc + cA, rc + cA + 4, rc + cB, rc + cB + 4, x, y, z, w4);
                vA[0] = x.x * inv; vA[1] = x.y * inv; vA[2] = x.z * inv; vA[3] = x.w * inv;
                vA[4] = y.x * inv; vA[5] = y.y * inv; vA[6] = y.z * inv; vA[7] = y.w * inv;
                vB[0] = z.x * inv; vB[1] = z.y * inv; vB[2] = z.z * inv; vB[3] = z.w * inv;
                vB[4] = w4.x * inv; vB[5] = w4.y * inv; vB[6] = w4.z * inv; vB[7] = w4.w * inv;
            }
            __syncthreads();                  // prior phase's smem readers done
            if (tid < RPB) smem[tid] = 0.f;
            __syncthreads();
#pragma unroll
            for (int r = 0; r < RPB; ++r) {   // row dots (A from registers)
                float f[8];
                up8(arA[r], f);
                float sp = f[0] * vA[0] + f[1] * vA[1] + f[2] * vA[2] + f[3] * vA[3]
                         + f[4] * vA[4] + f[5] * vA[5] + f[6] * vA[6] + f[7] * vA[7];
                up8(arB[r], f);
                sp += f[0] * vB[0] + f[1] * vB[1] + f[2] * vB[2] + f[3] * vB[3]
                    + f[4] * vB[4] + f[5] * vB[5] + f[6] * vB[6] + f[7] * vB[7];
#pragma unroll
                for (int off = 32; off > 0; off >>= 1) sp += __shfl_xor(sp, off);
                if (lane == 0) atomicAdd(&smem[r], sp);
            }
            __syncthreads();
            if (tid == 0) {                   // alpha += sum_r s_r^2 (1 atomic)
                float aa = 0.f;
#pragma unroll
                for (int r = 0; r < RPB; ++r) aa += smem[r] * smem[r];
                atomicAdd(&slots[j], aa);
            }
            float wacc[16];
#pragma unroll
            for (int i = 0; i < 16; ++i) wacc[i] = 0.f;
#pragma unroll
            for (int r = 0; r < RPB; ++r) {   // w += s_r * A_r (per-thread)
                float s = smem[r];
                float f[8];
                up8(arA[r], f);
                wacc[0] += s * f[0]; wacc[1] += s * f[1]; wacc[2] += s * f[2]; wacc[3] += s * f[3];
                wacc[4] += s * f[4]; wacc[5] += s * f[5]; wacc[6] += s * f[6]; wacc[7] += s * f[7];
                up8(arB[r], f);
                wacc[8] += s * f[0]; wacc[9] += s * f[1]; wacc[10] += s * f[2]; wacc[11] += s * f[3];
                wacc[12] += s * f[4]; wacc[13] += s * f[5]; wacc[14] += s * f[6]; wacc[15] += s * f[7];
            }
            float* pb = partials + (size_t)bid * NCOLS;        // write-through
            ic_st4_f32(pb + cA,     make_float4(wacc[0], wacc[1], wacc[2], wacc[3]));
            ic_st4_f32(pb + cA + 4, make_float4(wacc[4], wacc[5], wacc[6], wacc[7]));
            ic_st4_f32(pb + cB,     make_float4(wacc[8], wacc[9], wacc[10], wacc[11]));
            ic_st4_f32(pb + cB + 4, make_float4(wacc[12], wacc[13], wacc[14], wacc[15]));
        }
        gbar(arrive, release, errw, ++gen, bid);

        if (j < T_STEPS) {
            // ------------- fused reduce: 512 partials -> w, recurrence, beta --
            // Block b owns cols [8b, 8b+8). Thread: q=tid&1 (col-quad),
            // p0=tid>>1; sums partial rows {p0, p0+128, p0+256, p0+384}.
            {
                int q = tid & 1, p0 = tid >> 1;
                const float* pb0 = partials + (size_t)p0 * NCOLS + bid * 8 + q * 4;
                float4 v0, v1, v2, v3;
                ic_ld4_f32x4(pb0, pb0 + (size_t)128 * NCOLS,
                             pb0 + (size_t)256 * NCOLS, pb0 + (size_t)384 * NCOLS,
                             v0, v1, v2, v3);
                float4 s;
                s.x = v0.x + v1.x + v2.x + v3.x;
                s.y = v0.y + v1.y + v2.y + v3.y;
                s.z = v0.z + v1.z + v2.z + v3.z;
                s.w = v0.w + v1.w + v2.w + v3.w;
#pragma unroll
                for (int off = 2; off <= 32; off <<= 1) {
                    s.x += __shfl_xor(s.x, off);
                    s.y += __shfl_xor(s.y, off);
                    s.z += __shfl_xor(s.z, off);
                    s.w += __shfl_xor(s.w, off);
                }
                int lane = tid & 63, wv = tid >> 6;
                __syncthreads();              // bmv smem readers done
                if (lane < 2) *(float4*)&smem[32 + wv * 8 + lane * 4] = s;
                __syncthreads();
                if (tid < 8) {
                    int col = bid * 8 + tid;
                    float wsum = smem[32 + tid] + smem[40 + tid] + smem[48 + tid] + smem[56 + tid];
                    float a = ic_ld_f32(&slots[j]);
                    float n2j = fmaxf(ic_ld_f32(&slots[64 + j]), 1e-30f);
                    float n2m = fmaxf(ic_ld_f32(&slots[64 + j - 1]), 1e-30f);
                    float invj = rsqrtf(n2j);
                    float cb = sqrtf(n2j / n2m);               // beta_{j-1}/||r_{j-1}||
                    float rn = wsum - a * invj * ic_ld_f32(&rc[col]) - cb * ic_ld_f32(&rp[col]);
                    ic_st_f32(&wt[col], rn);                   // write-through
                    float p = rn * rn;
                    p += __shfl_xor(p, 1);
                    p += __shfl_xor(p, 2);
                    p += __shfl_xor(p, 4);
                    if (tid == 0) atomicAdd(&slots[64 + j + 1], p);
                }
            }
            gbar(arrive, release, errw, ++gen, bid);
        }
    }

    // ---------------- solve: largest eig of tridiag via Sturm (block 0) -------
    if (bid == 0) {
        const int t = T_STEPS;
        float* d_s = smem;
        float* e2_s = smem + 64;
        if (tid < 64) {
            d_s[tid] = (tid < t) ? ic_ld_f32(&slots[1 + tid]) : 0.f;
            e2_s[tid] = (tid < t - 1) ? ic_ld_f32(&slots[64 + tid + 2]) : 0.f;
        }
        __syncthreads();
        if (tid < 64) {
            int lane = tid;
            float e_here = sqrtf(e2_s[lane]);
            float e_prev = (lane > 0) ? sqrtf(e2_s[lane - 1]) : 0.f;
            float d = d_s[lane];
            float gersh = (lane < t) ? d + e_here + e_prev : 0.f;
            float dmax = (lane < t) ? d : 0.f;
#pragma unroll
            for (int off = 32; off > 0; off >>= 1) {
                gersh = fmaxf(gersh, __shfl_xor(gersh, off));
                dmax = fmaxf(dmax, __shfl_xor(dmax, off));
            }
            float lo = dmax, hi = gersh + 1e-3f;
            for (int round = 0; round < 3; ++round) {
                float stepw = (hi - lo) * (1.f / 64.f);
                float x = lo + stepw * (lane + 1);
                double qv = 1.0;
                int cnt = 0;
                for (int i = 0; i < t; ++i) {
                    double qi = (double)d_s[i] - (double)x - ((i > 0) ? (double)e2_s[i - 1] / qv : 0.0);
                    if (fabs(qi) < 1e-300) qi = -1e-300;
                    cnt += (qi < 0.0);
                    qv = qi;
                }
                unsigned long long m = __ballot(cnt < t);
                if (m) {
                    int h = 63 - __clzll(m);
                    lo = lo + stepw * (h + 1);
                    hi = lo + stepw;
                } else {
                    hi = lo + stepw;
                }
            }
            if (tid == 0) {
                unsigned e = ic_ld_u32(errw);
                out[0] = e ? (-1.0e7f - (float)e) : 0.5f * (lo + hi);
            }
        }
    }
}

extern "C" void kernel_launch(void* const* d_in, const int* in_sizes, int n_in,
                              void* d_out, int out_size, void* d_ws, size_t ws_size,
                              hipStream_t stream) {
    const float* A = (const float*)d_in[0];
    float* out = (float*)d_out;
    float* ws = (float*)d_ws;

    // Zero barrier state: 64 arrive lines + 64 release lines + err (12 KiB).
    hipMemsetAsync((char*)d_ws + (size_t)12416 * 4, 0, 12288, stream);

    lanczos_fused<<<NBLK, 256, 0, stream>>>(A, ws, out);
}